// Round 8
// baseline (172.605 us; speedup 1.0000x reference)
//
#include <hip/hip_runtime.h>

// Problem constants (from reference setup_inputs) — all tensors are fp32.
#define BATCH 16
#define NVEC 1024
#define NDIM 64
#define NHID 32
#define NW   10
#define NCLS 10
#define NOFF 11      // diag + 10 power-of-2 offsets (chord mask: 11 nnz/row)
#define NROWS (BATCH * NVEC)   // 16384 flat rows

// ---------------------------------------------------------------------------
// Kernel 0: transpose fW2 [i][j][m] -> W2T [i][m][j] so gather reads a row of
// 32 consecutive j's as 2 float4. LDS-tiled, 1.3 MB total.
// ---------------------------------------------------------------------------
__global__ __launch_bounds__(256) void k_transpose(
    const float* __restrict__ fW2, float* __restrict__ W2T)
{
    __shared__ float tile[NHID][65];
    const int i = blockIdx.y;
    const int m0 = blockIdx.x * 64;
    const int t = threadIdx.x;
    const int tL = t & 63, wv = t >> 6;

    const float* src = fW2 + (size_t)i * NHID * NVEC;
    #pragma unroll
    for (int jj = 0; jj < 8; ++jj) {
        int j = wv * 8 + jj;
        tile[j][tL] = src[(size_t)j * NVEC + m0 + tL];   // 256B coalesced
    }
    __syncthreads();

    float* dst = W2T + (size_t)i * NVEC * NHID;
    const int j = t & 31, mrow = t >> 5;
    #pragma unroll
    for (int g = 0; g < 8; ++g) {
        int m = g * 8 + mrow;
        dst[(size_t)(m0 + m) * NHID + j] = tile[j][m];   // coalesced
    }
}

// ---------------------------------------------------------------------------
// Kernel 1: H[i][flat][j] = gelu(data[flat,:] @ W1[i] + b1[i]) for all layers.
// Rounds 6/7 were stuck at ~55us: serial scalar-load chains + 4x jq re-read
// of data through L3. Here data is staged once per block into a TRANSPOSED
// padded LDS tile (dT[d][r], pad 65 -> conflict-free b32 reads), W1 comes in
// via wave-uniform s_loads (jq = wave id), and each (row, jq) thread does a
// pure FMA stream. Data logical traffic drops to 40MB; every global access
// is coalesced. grid (NROWS/64, NW), block 256 (4 waves), ~17KB LDS.
// ---------------------------------------------------------------------------
__global__ __launch_bounds__(256) void k_hidden(
    const float* __restrict__ data,   // [NROWS][NDIM]
    const float* __restrict__ fW1,    // [NW][NDIM][NHID]
    const float* __restrict__ fb1,    // [NW][NHID]
    float* __restrict__ H)            // [NW][NROWS][NHID]
{
    const int i = blockIdx.y;
    const int flat0 = blockIdx.x * 64;
    const int t = threadIdx.x;

    __shared__ float dT[NDIM][65];    // [d][row], pad 65: 2-way max (free)

    // stage 64 rows x 64 dims, transposed in flight; float4 global loads
    {
        const float4* src = (const float4*)(data + (size_t)flat0 * NDIM);
        #pragma unroll
        for (int q = 0; q < 4; ++q) {
            int fidx = t + 256 * q;           // float4 index in tile
            int r  = fidx >> 4;               // row 0..63
            int d4 = fidx & 15;               // float4 within row
            float4 u = src[fidx];
            dT[d4 * 4 + 0][r] = u.x;
            dT[d4 * 4 + 1][r] = u.y;
            dT[d4 * 4 + 2][r] = u.z;
            dT[d4 * 4 + 3][r] = u.w;
        }
    }
    __syncthreads();

    const int r  = t & 63;
    const int jq = t >> 6;            // wave id -> wave-uniform j-slice
    const int j0 = jq * 8;

    const float* w1 = fW1 + (size_t)i * NDIM * NHID + j0;
    const float* b1 = fb1 + (size_t)i * NHID + j0;

    float h[8];
    #pragma unroll
    for (int jj = 0; jj < 8; ++jj) h[jj] = b1[jj];

    #pragma unroll 8
    for (int d = 0; d < NDIM; ++d) {
        float x = dT[d][r];
        const float* wr = w1 + d * NHID;      // wave-uniform -> SGPR operand
        #pragma unroll
        for (int jj = 0; jj < 8; ++jj) h[jj] += x * wr[jj];
    }

    #pragma unroll
    for (int jj = 0; jj < 8; ++jj) {
        float x = h[jj];
        h[jj] = 0.5f * x * (1.0f + erff(x * 0.70710678118654752f));
    }

    float4* hp = (float4*)(H + ((size_t)i * NROWS + flat0 + r) * NHID + j0);
    hp[0] = make_float4(h[0], h[1], h[2], h[3]);
    hp[1] = make_float4(h[4], h[5], h[6], h[7]);
}

// ---------------------------------------------------------------------------
// Kernel 2: Wsp[i][b][o][n] = H[i][b*1024+n] . W2T[i][(n+off_o)%1024] + fb2.
// Key: for consecutive n-lanes the "gather" is a SHIFTED CONTIGUOUS stream
// (m = n+off consecutive) -> every load coalesced; all 41 loads per thread
// (8 H + 22 W2T + 11 b2) independent -> deep MLP. The 16 b's of a block
// re-read the same 22KB of W2T -> L1 hits. Stores coalesced b32.
// grid (NVEC/16, NW), block 256 = (16 n-lanes x 16 b).
// ---------------------------------------------------------------------------
__global__ __launch_bounds__(256) void k_gatherw(
    const float* __restrict__ H,      // [NW][NROWS][NHID]
    const float* __restrict__ W2T,    // [NW][NVEC][NHID]
    const float* __restrict__ fb2,    // [NW][NVEC]
    float* __restrict__ Wsp)          // [NW][BATCH][NOFF][NVEC]
{
    const int i  = blockIdx.y;
    const int t  = threadIdx.x;
    const int nl = t & 15;
    const int b  = t >> 4;
    const int n  = blockIdx.x * 16 + nl;

    // H row (8 float4, coalesced 2KB per 16 n-lanes)
    const float4* hp = (const float4*)(H + ((size_t)i * NROWS + b * NVEC + n) * NHID);
    float hh[NHID];
    #pragma unroll
    for (int k = 0; k < 8; ++k) {
        float4 u = hp[k];
        hh[k * 4 + 0] = u.x; hh[k * 4 + 1] = u.y;
        hh[k * 4 + 2] = u.z; hh[k * 4 + 3] = u.w;
    }

    const float* w2t = W2T + (size_t)i * NVEC * NHID;
    const float* b2  = fb2 + (size_t)i * NVEC;
    float* wout = Wsp + ((size_t)(i * BATCH + b) * NOFF) * NVEC + n;

    #pragma unroll
    for (int o = 0; o < NOFF; ++o) {
        int off = (1 << o) >> 1;              // 0,1,2,...,512
        int m = (n + off) & (NVEC - 1);
        const float4* gp = (const float4*)(w2t + (size_t)m * NHID);
        float acc = b2[m];
        #pragma unroll
        for (int k = 0; k < 8; ++k) {
            float4 g = gp[k];
            acc += hh[k * 4 + 0] * g.x + hh[k * 4 + 1] * g.y
                 + hh[k * 4 + 2] * g.z + hh[k * 4 + 3] * g.w;
        }
        wout[o * NVEC] = acc;                 // coalesced across n-lanes
    }
}

// ---------------------------------------------------------------------------
// Kernel 3: FUSED 10-layer chain + final-projection partials.
// Block = (b, 4-dim chunk): V[1024][4] slice closed under the chord gather,
// kept in LDS float4 (aligned ds_read_b128). 1024 threads = 16 waves. Next
// layer's 11 weights ([o][n] layout: 11 coalesced b32) prefetched into regs,
// in flight across the barrier. 1 barrier/layer. grid (16, BATCH), block 1024.
// ---------------------------------------------------------------------------
__global__ __launch_bounds__(1024) void k_chain(
    const float* __restrict__ data,   // [NROWS][NDIM]
    const float* __restrict__ Wsp,    // [NW][BATCH][NOFF][NVEC]
    const float* __restrict__ Wf,     // [NVEC*NDIM][NCLS]
    float* __restrict__ part)         // [B][16][NCLS]
{
    const int chunk = blockIdx.x;
    const int b     = blockIdx.y;
    const int d0    = chunk * 4;
    const int n     = threadIdx.x;

    __shared__ float4 bufA[NVEC];
    __shared__ float4 bufB[NVEC];

    bufA[n] = *(const float4*)(data + ((size_t)(b * NVEC) + n) * NDIM + d0);

    // prefetch layer NW-1 weights (11 coalesced b32 loads)
    float w[NOFF];
    {
        const float* wb = Wsp + ((size_t)((NW - 1) * BATCH + b) * NOFF) * NVEC + n;
        #pragma unroll
        for (int o = 0; o < NOFF; ++o) w[o] = wb[o * NVEC];
    }
    __syncthreads();

    float4* cur = bufA;
    float4* nxt = bufB;

    for (int l = 0; l < NW; ++l) {
        float nw[NOFF];
        if (l < NW - 1) {   // prefetch next layer (in flight across barrier)
            const float* wb = Wsp + ((size_t)((NW - 2 - l) * BATCH + b) * NOFF) * NVEC + n;
            #pragma unroll
            for (int o = 0; o < NOFF; ++o) nw[o] = wb[o * NVEC];
        }
        float4 v0 = cur[n];
        float4 acc;
        acc.x = v0.x + w[0] * v0.x;
        acc.y = v0.y + w[0] * v0.y;
        acc.z = v0.z + w[0] * v0.z;
        acc.w = v0.w + w[0] * v0.w;
        #pragma unroll
        for (int o = 1; o < NOFF; ++o) {
            int off = 1 << (o - 1);
            float4 vv = cur[(n + off) & (NVEC - 1)];
            acc.x += w[o] * vv.x; acc.y += w[o] * vv.y;
            acc.z += w[o] * vv.z; acc.w += w[o] * vv.w;
        }
        nxt[n] = acc;
        __syncthreads();
        float4* tmp = cur; cur = nxt; nxt = tmp;
        if (l < NW - 1) {
            #pragma unroll
            for (int o = 0; o < NOFF; ++o) w[o] = nw[o];
        }
    }

    // fused final projection partial over this (b, d-chunk)
    float p[NCLS];
    #pragma unroll
    for (int c = 0; c < NCLS; ++c) p[c] = 0.0f;
    {
        float4 vv = cur[n];
        float vs[4] = {vv.x, vv.y, vv.z, vv.w};
        const float4* wfv = (const float4*)(Wf + ((size_t)(n * NDIM + d0)) * NCLS);
        float wf[40];
        #pragma unroll
        for (int k = 0; k < 10; ++k) {
            float4 u = wfv[k];
            wf[k * 4 + 0] = u.x; wf[k * 4 + 1] = u.y;
            wf[k * 4 + 2] = u.z; wf[k * 4 + 3] = u.w;
        }
        #pragma unroll
        for (int d = 0; d < 4; ++d)
            #pragma unroll
            for (int cls = 0; cls < NCLS; ++cls)
                p[cls] += vs[d] * wf[d * NCLS + cls];
    }

    // reduce 1024 threads -> 10 values: wave shfl then cross-wave via LDS
    const int lane = n & 63, wv = n >> 6;   // 16 waves
    float* sred = (float*)nxt;              // dead buffer
    #pragma unroll
    for (int cls = 0; cls < NCLS; ++cls) {
        float v = p[cls];
        #pragma unroll
        for (int s = 32; s > 0; s >>= 1) v += __shfl_down(v, s, 64);
        if (lane == 0) sred[wv * NCLS + cls] = v;
    }
    __syncthreads();
    if (n < NCLS) {
        float s = 0.0f;
        #pragma unroll
        for (int w2 = 0; w2 < 16; ++w2) s += sred[w2 * NCLS + n];
        part[(size_t)(b * 16 + chunk) * NCLS + n] = s;
    }
}

// ---------------------------------------------------------------------------
__global__ __launch_bounds__(256) void k_finish(
    const float* __restrict__ part, const float* __restrict__ bias,
    float* __restrict__ out)
{
    int t = threadIdx.x;
    if (t < BATCH * NCLS) {
        int b = t / NCLS, cls = t % NCLS;
        float s = bias[cls];
        #pragma unroll
        for (int ch = 0; ch < 16; ++ch) s += part[(size_t)(b * 16 + ch) * NCLS + cls];
        out[t] = s;
    }
}

// ---------------------------------------------------------------------------
extern "C" void kernel_launch(void* const* d_in, const int* in_sizes, int n_in,
                              void* d_out, int out_size, void* d_ws, size_t ws_size,
                              hipStream_t stream) {
    const float* data = (const float*)d_in[0];
    const float* fW1  = (const float*)d_in[1];
    const float* fb1  = (const float*)d_in[2];
    const float* fW2  = (const float*)d_in[3];
    const float* fb2  = (const float*)d_in[4];
    const float* fWf  = (const float*)d_in[5];
    const float* fbf  = (const float*)d_in[6];
    float* out = (float*)d_out;

    float* ws   = (float*)d_ws;
    float* Wsp  = ws;                                       // 10*16*11*1024 = 1,802,240 f
    float* W2T  = Wsp + (size_t)NW * BATCH * NOFF * NVEC;   // 327,680 f
    float* H    = W2T + (size_t)NW * NVEC * NHID;           // 10*16384*32 = 5,242,880 f
    float* part = H + (size_t)NW * NROWS * NHID;            // 2,560 f

    k_transpose<<<dim3(NVEC / 64, NW), 256, 0, stream>>>(fW2, W2T);
    k_hidden<<<dim3(NROWS / 64, NW), 256, 0, stream>>>(data, fW1, fb1, H);
    k_gatherw<<<dim3(NVEC / 16, NW), 256, 0, stream>>>(H, W2T, fb2, Wsp);
    k_chain<<<dim3(NDIM / 4, BATCH), 1024, 0, stream>>>(data, Wsp, fWf, part);
    k_finish<<<dim3(1), 256, 0, stream>>>(part, fbf, out);
}

// Round 9
// 154.514 us; speedup vs baseline: 1.1171x; 1.1171x over previous
//
#include <hip/hip_runtime.h>

// Problem constants (from reference setup_inputs) — all tensors are fp32.
#define BATCH 16
#define NVEC 1024
#define NDIM 64
#define NHID 32
#define NW   10
#define NCLS 10
#define NOFF 11      // diag + 10 power-of-2 offsets (chord mask: 11 nnz/row)
#define NROWS (BATCH * NVEC)   // 16384 flat rows
#define RT   128     // rows per k_hidden block
#define LP   2       // layers per k_hidden block

// ---------------------------------------------------------------------------
// Kernel 0: transpose fW2 [i][j][m] -> W2T [i][m][j].
// ---------------------------------------------------------------------------
__global__ __launch_bounds__(256) void k_transpose(
    const float* __restrict__ fW2, float* __restrict__ W2T)
{
    __shared__ float tile[NHID][65];
    const int i = blockIdx.y;
    const int m0 = blockIdx.x * 64;
    const int t = threadIdx.x;
    const int tL = t & 63, wv = t >> 6;

    const float* src = fW2 + (size_t)i * NHID * NVEC;
    #pragma unroll
    for (int jj = 0; jj < 8; ++jj) {
        int j = wv * 8 + jj;
        tile[j][tL] = src[(size_t)j * NVEC + m0 + tL];
    }
    __syncthreads();

    float* dst = W2T + (size_t)i * NVEC * NHID;
    const int j = t & 31, mrow = t >> 5;
    #pragma unroll
    for (int g = 0; g < 8; ++g) {
        int m = g * 8 + mrow;
        dst[(size_t)(m0 + m) * NHID + j] = tile[j][m];
    }
}

// ---------------------------------------------------------------------------
// Kernel 1: H[i][flat][j] = gelu(data @ W1[i] + b1[i]) as a REAL LDS GEMM.
// Rounds 6-8 all fed W1 from global/scalar memory in the K-loop -> 17-24%
// VALUBusy, ~50us. Here: A-tile AND W-tile in LDS, thread-tile 8 rows x 8
// jcols (64 FMA per 4 ds_read_b128 = 2.7:1 VALU:LDS -> VALU-bound).
// A stored transposed with row-permutation sigma(r)=((r>>2)&1)*64+(r>>3)*4
// +(r&3): each thread's 8 rows = two conflict-free b128 (lanes dense,
// 4-lane broadcast). Staging: thread t owns row t (global reads contiguous
// per lane; LDS writes 2-way = free). Block = 128 rows x 2 layers (64 jcol),
// 128 threads. grid (NROWS/128, NW/2) = 640 blocks.
// ---------------------------------------------------------------------------
__global__ __launch_bounds__(128) void k_hidden(
    const float* __restrict__ data,   // [NROWS][NDIM]
    const float* __restrict__ fW1,    // [NW][NDIM][NHID]
    const float* __restrict__ fb1,    // [NW][NHID]
    float* __restrict__ H)            // [NW][NROWS][NHID]
{
    const int i0    = blockIdx.y * LP;
    const int flat0 = blockIdx.x * RT;
    const int t     = threadIdx.x;    // 0..127
    const int rowg  = t & 15;         // 8-row group (rows 8*rowg..+7)
    const int jg    = t >> 4;         // 0..7 -> jcol0 = jg*8

    __shared__ float sA[32][RT];      // [k][sigma(row)], 16 KB, stride 128 f
    __shared__ float sW[64][64];      // [k][jcol], 16 KB
    __shared__ float sB[64];

    // stage W (both layers, all K) + bias: 1024 float4 / 128 threads
    #pragma unroll
    for (int q = 0; q < 8; ++q) {
        int idx = t + 128 * q;
        int k = idx >> 4, jc4 = idx & 15;
        int layer = jc4 >> 3, j4 = jc4 & 7;
        float4 u = *(const float4*)(fW1 + ((size_t)(i0 + layer) * NDIM + k) * NHID + j4 * 4);
        *(float4*)&sW[k][jc4 * 4] = u;
    }
    if (t < 64) sB[t] = fb1[(size_t)(i0 + (t >> 5)) * NHID + (t & 31)];

    float acc[8][8];
    #pragma unroll
    for (int r = 0; r < 8; ++r)
        #pragma unroll
        for (int j = 0; j < 8; ++j) acc[r][j] = 0.0f;

    // sigma(t): slot for staging row t
    const int sslot = ((t >> 2) & 1) * 64 + (t >> 3) * 4 + (t & 3);
    const float4* rowp = (const float4*)(data + (size_t)(flat0 + t) * NDIM);

    for (int kh = 0; kh < 2; ++kh) {
        // stage A half-K: thread t stages row t, k = kh*32..+31
        #pragma unroll
        for (int q = 0; q < 8; ++q) {
            float4 u = rowp[kh * 8 + q];
            sA[q * 4 + 0][sslot] = u.x;
            sA[q * 4 + 1][sslot] = u.y;
            sA[q * 4 + 2][sslot] = u.z;
            sA[q * 4 + 3][sslot] = u.w;
        }
        __syncthreads();

        #pragma unroll 2
        for (int kk = 0; kk < 32; ++kk) {
            float4 a0 = *(const float4*)&sA[kk][rowg * 4];        // rows 8g..+3
            float4 a1 = *(const float4*)&sA[kk][64 + rowg * 4];   // rows 8g+4..+7
            float4 w0 = *(const float4*)&sW[kh * 32 + kk][jg * 8];
            float4 w1 = *(const float4*)&sW[kh * 32 + kk][jg * 8 + 4];
            float av[8] = {a0.x, a0.y, a0.z, a0.w, a1.x, a1.y, a1.z, a1.w};
            float wv[8] = {w0.x, w0.y, w0.z, w0.w, w1.x, w1.y, w1.z, w1.w};
            #pragma unroll
            for (int r = 0; r < 8; ++r)
                #pragma unroll
                for (int j = 0; j < 8; ++j) acc[r][j] += av[r] * wv[j];
        }
        __syncthreads();   // before restaging / before epilogue reuse
    }

    // epilogue: bias + exact gelu, store H
    const int layer = jg >> 2;
    const int j0    = (jg & 3) * 8;
    #pragma unroll
    for (int rr = 0; rr < 8; ++rr) {
        int row = flat0 + rowg * 8 + rr;
        float hv[8];
        #pragma unroll
        for (int jj = 0; jj < 8; ++jj) {
            float x = acc[rr][jj] + sB[jg * 8 + jj];
            hv[jj] = 0.5f * x * (1.0f + erff(x * 0.70710678118654752f));
        }
        float4* hp = (float4*)(H + ((size_t)(i0 + layer) * NROWS + row) * NHID + j0);
        hp[0] = make_float4(hv[0], hv[1], hv[2], hv[3]);
        hp[1] = make_float4(hv[4], hv[5], hv[6], hv[7]);
    }
}

// ---------------------------------------------------------------------------
// Kernel 2: Wsp[i][b][o][n] = H[i][b*1024+n] . W2T[i][(n+off_o)%1024] + fb2.
// For consecutive n-lanes the gather is a shifted contiguous stream; all
// loads coalesced and independent. grid (NVEC/16, NW), block 256.
// ---------------------------------------------------------------------------
__global__ __launch_bounds__(256) void k_gatherw(
    const float* __restrict__ H,      // [NW][NROWS][NHID]
    const float* __restrict__ W2T,    // [NW][NVEC][NHID]
    const float* __restrict__ fb2,    // [NW][NVEC]
    float* __restrict__ Wsp)          // [NW][BATCH][NOFF][NVEC]
{
    const int i  = blockIdx.y;
    const int t  = threadIdx.x;
    const int nl = t & 15;
    const int b  = t >> 4;
    const int n  = blockIdx.x * 16 + nl;

    const float4* hp = (const float4*)(H + ((size_t)i * NROWS + b * NVEC + n) * NHID);
    float hh[NHID];
    #pragma unroll
    for (int k = 0; k < 8; ++k) {
        float4 u = hp[k];
        hh[k * 4 + 0] = u.x; hh[k * 4 + 1] = u.y;
        hh[k * 4 + 2] = u.z; hh[k * 4 + 3] = u.w;
    }

    const float* w2t = W2T + (size_t)i * NVEC * NHID;
    const float* b2  = fb2 + (size_t)i * NVEC;
    float* wout = Wsp + ((size_t)(i * BATCH + b) * NOFF) * NVEC + n;

    #pragma unroll
    for (int o = 0; o < NOFF; ++o) {
        int off = (1 << o) >> 1;
        int m = (n + off) & (NVEC - 1);
        const float4* gp = (const float4*)(w2t + (size_t)m * NHID);
        float acc = b2[m];
        #pragma unroll
        for (int k = 0; k < 8; ++k) {
            float4 g = gp[k];
            acc += hh[k * 4 + 0] * g.x + hh[k * 4 + 1] * g.y
                 + hh[k * 4 + 2] * g.z + hh[k * 4 + 3] * g.w;
        }
        wout[o * NVEC] = acc;
    }
}

// ---------------------------------------------------------------------------
// Kernel 3: FUSED 10-layer chain + final-projection partials.
// Block = (b, 4-dim chunk); V[1024][4] slice in LDS; weight prefetch across
// the barrier. grid (16, BATCH), block 1024.
// ---------------------------------------------------------------------------
__global__ __launch_bounds__(1024) void k_chain(
    const float* __restrict__ data,   // [NROWS][NDIM]
    const float* __restrict__ Wsp,    // [NW][BATCH][NOFF][NVEC]
    const float* __restrict__ Wf,     // [NVEC*NDIM][NCLS]
    float* __restrict__ part)         // [B][16][NCLS]
{
    const int chunk = blockIdx.x;
    const int b     = blockIdx.y;
    const int d0    = chunk * 4;
    const int n     = threadIdx.x;

    __shared__ float4 bufA[NVEC];
    __shared__ float4 bufB[NVEC];

    bufA[n] = *(const float4*)(data + ((size_t)(b * NVEC) + n) * NDIM + d0);

    float w[NOFF];
    {
        const float* wb = Wsp + ((size_t)((NW - 1) * BATCH + b) * NOFF) * NVEC + n;
        #pragma unroll
        for (int o = 0; o < NOFF; ++o) w[o] = wb[o * NVEC];
    }
    __syncthreads();

    float4* cur = bufA;
    float4* nxt = bufB;

    for (int l = 0; l < NW; ++l) {
        float nw[NOFF];
        if (l < NW - 1) {
            const float* wb = Wsp + ((size_t)((NW - 2 - l) * BATCH + b) * NOFF) * NVEC + n;
            #pragma unroll
            for (int o = 0; o < NOFF; ++o) nw[o] = wb[o * NVEC];
        }
        float4 v0 = cur[n];
        float4 acc;
        acc.x = v0.x + w[0] * v0.x;
        acc.y = v0.y + w[0] * v0.y;
        acc.z = v0.z + w[0] * v0.z;
        acc.w = v0.w + w[0] * v0.w;
        #pragma unroll
        for (int o = 1; o < NOFF; ++o) {
            int off = 1 << (o - 1);
            float4 vv = cur[(n + off) & (NVEC - 1)];
            acc.x += w[o] * vv.x; acc.y += w[o] * vv.y;
            acc.z += w[o] * vv.z; acc.w += w[o] * vv.w;
        }
        nxt[n] = acc;
        __syncthreads();
        float4* tmp = cur; cur = nxt; nxt = tmp;
        if (l < NW - 1) {
            #pragma unroll
            for (int o = 0; o < NOFF; ++o) w[o] = nw[o];
        }
    }

    float p[NCLS];
    #pragma unroll
    for (int c = 0; c < NCLS; ++c) p[c] = 0.0f;
    {
        float4 vv = cur[n];
        float vs[4] = {vv.x, vv.y, vv.z, vv.w};
        const float4* wfv = (const float4*)(Wf + ((size_t)(n * NDIM + d0)) * NCLS);
        float wf[40];
        #pragma unroll
        for (int k = 0; k < 10; ++k) {
            float4 u = wfv[k];
            wf[k * 4 + 0] = u.x; wf[k * 4 + 1] = u.y;
            wf[k * 4 + 2] = u.z; wf[k * 4 + 3] = u.w;
        }
        #pragma unroll
        for (int d = 0; d < 4; ++d)
            #pragma unroll
            for (int cls = 0; cls < NCLS; ++cls)
                p[cls] += vs[d] * wf[d * NCLS + cls];
    }

    const int lane = n & 63, wv = n >> 6;
    float* sred = (float*)nxt;
    #pragma unroll
    for (int cls = 0; cls < NCLS; ++cls) {
        float v = p[cls];
        #pragma unroll
        for (int s = 32; s > 0; s >>= 1) v += __shfl_down(v, s, 64);
        if (lane == 0) sred[wv * NCLS + cls] = v;
    }
    __syncthreads();
    if (n < NCLS) {
        float s = 0.0f;
        #pragma unroll
        for (int w2 = 0; w2 < 16; ++w2) s += sred[w2 * NCLS + n];
        part[(size_t)(b * 16 + chunk) * NCLS + n] = s;
    }
}

// ---------------------------------------------------------------------------
__global__ __launch_bounds__(256) void k_finish(
    const float* __restrict__ part, const float* __restrict__ bias,
    float* __restrict__ out)
{
    int t = threadIdx.x;
    if (t < BATCH * NCLS) {
        int b = t / NCLS, cls = t % NCLS;
        float s = bias[cls];
        #pragma unroll
        for (int ch = 0; ch < 16; ++ch) s += part[(size_t)(b * 16 + ch) * NCLS + cls];
        out[t] = s;
    }
}

// ---------------------------------------------------------------------------
extern "C" void kernel_launch(void* const* d_in, const int* in_sizes, int n_in,
                              void* d_out, int out_size, void* d_ws, size_t ws_size,
                              hipStream_t stream) {
    const float* data = (const float*)d_in[0];
    const float* fW1  = (const float*)d_in[1];
    const float* fb1  = (const float*)d_in[2];
    const float* fW2  = (const float*)d_in[3];
    const float* fb2  = (const float*)d_in[4];
    const float* fWf  = (const float*)d_in[5];
    const float* fbf  = (const float*)d_in[6];
    float* out = (float*)d_out;

    float* ws   = (float*)d_ws;
    float* Wsp  = ws;                                       // 1,802,240 f
    float* W2T  = Wsp + (size_t)NW * BATCH * NOFF * NVEC;   // 327,680 f
    float* H    = W2T + (size_t)NW * NVEC * NHID;           // 5,242,880 f
    float* part = H + (size_t)NW * NROWS * NHID;            // 2,560 f

    k_transpose<<<dim3(NVEC / 64, NW), 256, 0, stream>>>(fW2, W2T);
    k_hidden<<<dim3(NROWS / RT, NW / LP), 128, 0, stream>>>(data, fW1, fb1, H);
    k_gatherw<<<dim3(NVEC / 16, NW), 256, 0, stream>>>(H, W2T, fb2, Wsp);
    k_chain<<<dim3(NDIM / 4, BATCH), 1024, 0, stream>>>(data, Wsp, fWf, part);
    k_finish<<<dim3(1), 256, 0, stream>>>(part, fbf, out);
}

// Round 10
// 136.954 us; speedup vs baseline: 1.2603x; 1.1282x over previous
//
#include <hip/hip_runtime.h>

// Problem constants (from reference setup_inputs) — all tensors are fp32.
#define BATCH 16
#define NVEC 1024
#define NDIM 64
#define NHID 32
#define NW   10
#define NCLS 10
#define NOFF 11      // diag + 10 power-of-2 offsets (chord mask: 11 nnz/row)
#define NROWS (BATCH * NVEC)   // 16384 flat rows

// ---------------------------------------------------------------------------
// Kernel 0: transpose fW2 [i][j][m] -> W2T [i][m][j].
// ---------------------------------------------------------------------------
__global__ __launch_bounds__(256) void k_transpose(
    const float* __restrict__ fW2, float* __restrict__ W2T)
{
    __shared__ float tile[NHID][65];
    const int i = blockIdx.y;
    const int m0 = blockIdx.x * 64;
    const int t = threadIdx.x;
    const int tL = t & 63, wv = t >> 6;

    const float* src = fW2 + (size_t)i * NHID * NVEC;
    #pragma unroll
    for (int jj = 0; jj < 8; ++jj) {
        int j = wv * 8 + jj;
        tile[j][tL] = src[(size_t)j * NVEC + m0 + tL];
    }
    __syncthreads();

    float* dst = W2T + (size_t)i * NVEC * NHID;
    const int j = t & 31, mrow = t >> 5;
    #pragma unroll
    for (int g = 0; g < 8; ++g) {
        int m = g * 8 + mrow;
        dst[(size_t)(m0 + m) * NHID + j] = tile[j][m];
    }
}

// ---------------------------------------------------------------------------
// Kernel 1 (FUSED): hidden GEMM + gelu + chord gather -> Wsp, one layer and
// 256 contiguous flat rows per block. The gather needs only the SAME row's h
// (Wsp[i,b,o,n] = h[b,n]·W2T[m_o]+b2), so h never leaves the block: round-9
// materialized 21MB H through HBM (42MB round trip) + an extra dispatch.
// GEMM: 256 threads = 32 rowg x 8 jg, tile 8 rows x 4 j (32 accs, ~70 VGPR,
// no spill), sA[32][256] (half-K staged twice) + sW[64][32] in LDS; per k:
// 3 ds_read_b128 (36 cyc) vs 32 FMA (64 cyc) -> VALU-bound. 3 blocks/CU =
// 12 waves/CU (round 9 ran 1.25 waves/SIMD -> latency-bound at ~30us).
// Gather: h-tile in LDS (pad 33, b32 reads conflict-free), W2T rows m=n+off
// are shifted contiguous streams (coalesced), Wsp stores coalesced over n.
// grid (NROWS/256, NW), block 256.
// ---------------------------------------------------------------------------
__global__ __launch_bounds__(256) void k_hg(
    const float* __restrict__ data,   // [NROWS][NDIM]
    const float* __restrict__ fW1,    // [NW][NDIM][NHID]
    const float* __restrict__ fb1,    // [NW][NHID]
    const float* __restrict__ W2T,    // [NW][NVEC][NHID]
    const float* __restrict__ fb2,    // [NW][NVEC]
    float* __restrict__ Wsp)          // [NW][BATCH][NOFF][NVEC]
{
    const int i     = blockIdx.y;
    const int flat0 = blockIdx.x * 256;       // = b*1024 + n0 (256-aligned)
    const int b     = flat0 >> 10;
    const int n0    = flat0 & (NVEC - 1);
    const int t     = threadIdx.x;
    const int rowg  = t >> 3;                 // 0..31 -> rows 8*rowg..+7
    const int jg    = t & 7;                  // 0..7  -> j0 = 4*jg

    // LDS: GEMM region [sA 32KB | sW 8KB] overlaid by H[256][33] after GEMM
    __shared__ float lds[32 * 256 + 64 * 32]; // 40 KB
    float* sA = lds;                          // [k][row] k<32(half), row<256
    float* sW = lds + 32 * 256;               // [k][j]   k<64, j<32
    float* sH = lds;                          // [row][33] after GEMM (33.8KB)
    __shared__ float sB[NHID];

    // stage W1 (K=64 x 32j = 512 float4 / 256 thr = 2 each) + bias
    {
        const float4* w1v = (const float4*)(fW1 + (size_t)i * NDIM * NHID);
        float4* s4 = (float4*)sW;
        s4[t] = w1v[t];
        s4[t + 256] = w1v[t + 256];
        if (t < NHID) sB[t] = fb1[(size_t)i * NHID + t];
    }

    float acc[8][4];
    #pragma unroll
    for (int r = 0; r < 8; ++r)
        #pragma unroll
        for (int j = 0; j < 4; ++j) acc[r][j] = 0.0f;

    const float4* rowp = (const float4*)(data + (size_t)(flat0 + t) * NDIM);

    for (int kh = 0; kh < 2; ++kh) {
        // stage A half-K transposed: thread t owns row t, k = kh*32..+31
        #pragma unroll
        for (int q = 0; q < 8; ++q) {
            float4 u = rowp[kh * 8 + q];
            sA[(q * 4 + 0) * 256 + t] = u.x;
            sA[(q * 4 + 1) * 256 + t] = u.y;
            sA[(q * 4 + 2) * 256 + t] = u.z;
            sA[(q * 4 + 3) * 256 + t] = u.w;
        }
        __syncthreads();

        #pragma unroll 4
        for (int kk = 0; kk < 32; ++kk) {
            float4 a0 = *(const float4*)&sA[kk * 256 + rowg * 8];
            float4 a1 = *(const float4*)&sA[kk * 256 + rowg * 8 + 4];
            float4 wv = *(const float4*)&sW[(kh * 32 + kk) * 32 + jg * 4];
            float av[8] = {a0.x, a0.y, a0.z, a0.w, a1.x, a1.y, a1.z, a1.w};
            float wf[4] = {wv.x, wv.y, wv.z, wv.w};
            #pragma unroll
            for (int r = 0; r < 8; ++r)
                #pragma unroll
                for (int j = 0; j < 4; ++j) acc[r][j] += av[r] * wf[j];
        }
        __syncthreads();   // sA reads done before restage / epilogue overlay
    }

    // epilogue: bias + exact gelu -> H-LDS (pad 33; banks 8g+4jg+c: 2-way max)
    #pragma unroll
    for (int rr = 0; rr < 8; ++rr) {
        int row = rowg * 8 + rr;
        #pragma unroll
        for (int jj = 0; jj < 4; ++jj) {
            float x = acc[rr][jj] + sB[jg * 4 + jj];
            sH[row * 33 + jg * 4 + jj] =
                0.5f * x * (1.0f + erff(x * 0.70710678118654752f));
        }
    }
    __syncthreads();

    // gather: thread t = row n0+t; h from LDS; W2T shifted contiguous streams
    const int n = n0 + t;
    float hh[NHID];
    #pragma unroll
    for (int j = 0; j < NHID; ++j) hh[j] = sH[t * 33 + j];   // bank (t+j)%32: clean

    const float* w2t = W2T + (size_t)i * NVEC * NHID;
    const float* b2  = fb2 + (size_t)i * NVEC;
    float* wout = Wsp + ((size_t)(i * BATCH + b) * NOFF) * NVEC + n;

    #pragma unroll
    for (int o = 0; o < NOFF; ++o) {
        int off = (1 << o) >> 1;              // 0,1,2,...,512
        int m = (n + off) & (NVEC - 1);
        const float4* gp = (const float4*)(w2t + (size_t)m * NHID);
        float a = b2[m];
        #pragma unroll
        for (int k = 0; k < 8; ++k) {
            float4 g = gp[k];
            a += hh[k * 4 + 0] * g.x + hh[k * 4 + 1] * g.y
               + hh[k * 4 + 2] * g.z + hh[k * 4 + 3] * g.w;
        }
        wout[o * NVEC] = a;                   // coalesced across n
    }
}

// ---------------------------------------------------------------------------
// Kernel 2: FUSED 10-layer chain + final-projection partials.
// Block = (b, 4-dim chunk); V[1024][4] slice in LDS; weight prefetch across
// the barrier. grid (16, BATCH), block 1024.
// ---------------------------------------------------------------------------
__global__ __launch_bounds__(1024) void k_chain(
    const float* __restrict__ data,   // [NROWS][NDIM]
    const float* __restrict__ Wsp,    // [NW][BATCH][NOFF][NVEC]
    const float* __restrict__ Wf,     // [NVEC*NDIM][NCLS]
    float* __restrict__ part)         // [B][16][NCLS]
{
    const int chunk = blockIdx.x;
    const int b     = blockIdx.y;
    const int d0    = chunk * 4;
    const int n     = threadIdx.x;

    __shared__ float4 bufA[NVEC];
    __shared__ float4 bufB[NVEC];

    bufA[n] = *(const float4*)(data + ((size_t)(b * NVEC) + n) * NDIM + d0);

    float w[NOFF];
    {
        const float* wb = Wsp + ((size_t)((NW - 1) * BATCH + b) * NOFF) * NVEC + n;
        #pragma unroll
        for (int o = 0; o < NOFF; ++o) w[o] = wb[o * NVEC];
    }
    __syncthreads();

    float4* cur = bufA;
    float4* nxt = bufB;

    for (int l = 0; l < NW; ++l) {
        float nw[NOFF];
        if (l < NW - 1) {
            const float* wb = Wsp + ((size_t)((NW - 2 - l) * BATCH + b) * NOFF) * NVEC + n;
            #pragma unroll
            for (int o = 0; o < NOFF; ++o) nw[o] = wb[o * NVEC];
        }
        float4 v0 = cur[n];
        float4 acc;
        acc.x = v0.x + w[0] * v0.x;
        acc.y = v0.y + w[0] * v0.y;
        acc.z = v0.z + w[0] * v0.z;
        acc.w = v0.w + w[0] * v0.w;
        #pragma unroll
        for (int o = 1; o < NOFF; ++o) {
            int off = 1 << (o - 1);
            float4 vv = cur[(n + off) & (NVEC - 1)];
            acc.x += w[o] * vv.x; acc.y += w[o] * vv.y;
            acc.z += w[o] * vv.z; acc.w += w[o] * vv.w;
        }
        nxt[n] = acc;
        __syncthreads();
        float4* tmp = cur; cur = nxt; nxt = tmp;
        if (l < NW - 1) {
            #pragma unroll
            for (int o = 0; o < NOFF; ++o) w[o] = nw[o];
        }
    }

    float p[NCLS];
    #pragma unroll
    for (int c = 0; c < NCLS; ++c) p[c] = 0.0f;
    {
        float4 vv = cur[n];
        float vs[4] = {vv.x, vv.y, vv.z, vv.w};
        const float4* wfv = (const float4*)(Wf + ((size_t)(n * NDIM + d0)) * NCLS);
        float wf[40];
        #pragma unroll
        for (int k = 0; k < 10; ++k) {
            float4 u = wfv[k];
            wf[k * 4 + 0] = u.x; wf[k * 4 + 1] = u.y;
            wf[k * 4 + 2] = u.z; wf[k * 4 + 3] = u.w;
        }
        #pragma unroll
        for (int d = 0; d < 4; ++d)
            #pragma unroll
            for (int cls = 0; cls < NCLS; ++cls)
                p[cls] += vs[d] * wf[d * NCLS + cls];
    }

    const int lane = n & 63, wv = n >> 6;
    float* sred = (float*)nxt;
    #pragma unroll
    for (int cls = 0; cls < NCLS; ++cls) {
        float v = p[cls];
        #pragma unroll
        for (int s = 32; s > 0; s >>= 1) v += __shfl_down(v, s, 64);
        if (lane == 0) sred[wv * NCLS + cls] = v;
    }
    __syncthreads();
    if (n < NCLS) {
        float s = 0.0f;
        #pragma unroll
        for (int w2 = 0; w2 < 16; ++w2) s += sred[w2 * NCLS + n];
        part[(size_t)(b * 16 + chunk) * NCLS + n] = s;
    }
}

// ---------------------------------------------------------------------------
__global__ __launch_bounds__(256) void k_finish(
    const float* __restrict__ part, const float* __restrict__ bias,
    float* __restrict__ out)
{
    int t = threadIdx.x;
    if (t < BATCH * NCLS) {
        int b = t / NCLS, cls = t % NCLS;
        float s = bias[cls];
        #pragma unroll
        for (int ch = 0; ch < 16; ++ch) s += part[(size_t)(b * 16 + ch) * NCLS + cls];
        out[t] = s;
    }
}

// ---------------------------------------------------------------------------
extern "C" void kernel_launch(void* const* d_in, const int* in_sizes, int n_in,
                              void* d_out, int out_size, void* d_ws, size_t ws_size,
                              hipStream_t stream) {
    const float* data = (const float*)d_in[0];
    const float* fW1  = (const float*)d_in[1];
    const float* fb1  = (const float*)d_in[2];
    const float* fW2  = (const float*)d_in[3];
    const float* fb2  = (const float*)d_in[4];
    const float* fWf  = (const float*)d_in[5];
    const float* fbf  = (const float*)d_in[6];
    float* out = (float*)d_out;

    float* ws   = (float*)d_ws;
    float* Wsp  = ws;                                       // 1,802,240 f
    float* W2T  = Wsp + (size_t)NW * BATCH * NOFF * NVEC;   // 327,680 f
    float* part = W2T + (size_t)NW * NVEC * NHID;           // 2,560 f

    k_transpose<<<dim3(NVEC / 64, NW), 256, 0, stream>>>(fW2, W2T);
    k_hg<<<dim3(NROWS / 256, NW), 256, 0, stream>>>(
        data, fW1, fb1, W2T, fb2, Wsp);
    k_chain<<<dim3(NDIM / 4, BATCH), 1024, 0, stream>>>(data, Wsp, fWf, part);
    k_finish<<<dim3(1), 256, 0, stream>>>(part, fbf, out);
}